// Round 3
// baseline (164.816 us; speedup 1.0000x reference)
//
#include <hip/hip_runtime.h>
#include <hip/hip_bf16.h>

// B=128, LQ=32, LD=256, HID=768, DIM=128
typedef __attribute__((ext_vector_type(8))) short short8;
typedef __attribute__((ext_vector_type(4))) float f32x4;
typedef __attribute__((ext_vector_type(16))) float f32x16;

#define MFMA16(a, b, c) __builtin_amdgcn_mfma_f32_16x16x32_bf16(a, b, c, 0, 0, 0)
#define MFMA32(a, b, c) __builtin_amdgcn_mfma_f32_32x32x16_bf16(a, b, c, 0, 0, 0)
#define LGKM0() asm volatile("s_waitcnt lgkmcnt(0)" ::: "memory")
#define RAW_BAR() do { __builtin_amdgcn_sched_barrier(0); \
                       __builtin_amdgcn_s_barrier(); \
                       __builtin_amdgcn_sched_barrier(0); } while (0)

__device__ __forceinline__ short f2bf(float f) {
    union { float f; unsigned u; } x; x.f = f;
    unsigned r = x.u + 0x7fffu + ((x.u >> 16) & 1u);  // RNE
    return (short)(r >> 16);
}

// ---------------------------------------------------------------------------
// Kernel 1: P[row][dim] = l2norm( X[row,:768] @ W[dim,:768]^T ), bf16 out.
// A = X rows (M), B = W (N=dim), K=hid. BM=64, BK=64, 12 K-steps.
// LDS double-buffered + reg double-buffered staging; RAW barriers (no vmcnt
// drain) -> chunk k+2 loads stay in flight across the barrier.
// ---------------------------------------------------------------------------
__global__ __launch_bounds__(256, 2) void proj_norm_kernel(
    const float* __restrict__ qh, const float* __restrict__ dh,
    const float* __restrict__ W, const int* __restrict__ dmask,
    unsigned short* __restrict__ Qb, unsigned short* __restrict__ Db)
{
    __shared__ __align__(16) short Xlds[2][64][72];    // 9.2 KB x2
    __shared__ __align__(16) short Wlds[2][128][72];   // 18.4 KB x2  (55.3 KB total)

    const int tid = threadIdx.x;
    const int wave = tid >> 6, lane = tid & 63;
    const int l = lane & 15, g = lane >> 4;

    const int rowbase = blockIdx.x * 64;            // Q rows first (4096), then D
    const bool isQ = rowbase < 4096;
    const float* X = isQ ? qh : dh;
    const int prow = isQ ? rowbase : rowbase - 4096;

    const int xrow = tid >> 2, xq = tid & 3;        // X: 4 thr/row, 16 floats each
    const int wrow = tid >> 1, wh = tid & 1;        // W: 2 thr/row, 32 floats each
    const float* xsrc = X + (size_t)(prow + xrow) * 768 + xq * 16;
    const float* wsrc = W + (size_t)wrow * 768 + wh * 32;

    float4 xa[4], wa[8], xb[4], wb[8];

    auto loadset = [&](float4 (&xr)[4], float4 (&wr)[8], int chunk) {
        const float4* xs = reinterpret_cast<const float4*>(xsrc + chunk * 64);
        const float4* ws = reinterpret_cast<const float4*>(wsrc + chunk * 64);
        #pragma unroll
        for (int i = 0; i < 4; ++i) xr[i] = xs[i];
        #pragma unroll
        for (int i = 0; i < 8; ++i) wr[i] = ws[i];
    };
    auto stage = [&](float4 (&xr)[4], float4 (&wr)[8], int p) {
        #pragma unroll
        for (int j = 0; j < 2; ++j) {
            short8 v;
            v[0]=f2bf(xr[2*j].x);   v[1]=f2bf(xr[2*j].y);
            v[2]=f2bf(xr[2*j].z);   v[3]=f2bf(xr[2*j].w);
            v[4]=f2bf(xr[2*j+1].x); v[5]=f2bf(xr[2*j+1].y);
            v[6]=f2bf(xr[2*j+1].z); v[7]=f2bf(xr[2*j+1].w);
            *reinterpret_cast<short8*>(&Xlds[p][xrow][xq * 16 + j * 8]) = v;
        }
        #pragma unroll
        for (int j = 0; j < 4; ++j) {
            short8 v;
            v[0]=f2bf(wr[2*j].x);   v[1]=f2bf(wr[2*j].y);
            v[2]=f2bf(wr[2*j].z);   v[3]=f2bf(wr[2*j].w);
            v[4]=f2bf(wr[2*j+1].x); v[5]=f2bf(wr[2*j+1].y);
            v[6]=f2bf(wr[2*j+1].z); v[7]=f2bf(wr[2*j+1].w);
            *reinterpret_cast<short8*>(&Wlds[p][wrow][wh * 32 + j * 8]) = v;
        }
    };

    f32x4 acc[8];
    #pragma unroll
    for (int n = 0; n < 8; ++n) acc[n] = (f32x4)(0.0f);

    // prologue: chunk0 -> buf0; issue chunk1
    loadset(xa, wa, 0);
    stage(xa, wa, 0);              // compiler inserts vmcnt wait before first use
    loadset(xb, wb, 1);
    LGKM0(); RAW_BAR();

    #pragma unroll
    for (int k = 0; k < 12; ++k) {
        const int p = k & 1;
        // --- compute chunk k from buf p (chunk k+1 loads in flight) ---
        #pragma unroll
        for (int ks = 0; ks < 2; ++ks) {
            short8 af = *reinterpret_cast<const short8*>(&Xlds[p][wave * 16 + l][ks * 32 + g * 8]);
            #pragma unroll
            for (int n = 0; n < 8; ++n) {
                short8 bf = *reinterpret_cast<const short8*>(&Wlds[p][n * 16 + l][ks * 32 + g * 8]);
                acc[n] = MFMA16(af, bf, acc[n]);
            }
        }
        if (k < 11) {
            // stage chunk k+1 into buf p^1; issue chunk k+2 into freed reg set
            if (p == 0) {
                stage(xb, wb, 1);
                if (k < 10) loadset(xa, wa, k + 2);
            } else {
                stage(xa, wa, 0);
                if (k < 10) loadset(xb, wb, k + 2);
            }
            LGKM0(); RAW_BAR();
        }
    }

    // --- L2 norm: lane holds C[row=g*4+r][dim=n*16+l] in acc[n][r] ---
    float rn[4];
    #pragma unroll
    for (int r = 0; r < 4; ++r) {
        float ss = 0.f;
        #pragma unroll
        for (int n = 0; n < 8; ++n) ss += acc[n][r] * acc[n][r];
        ss += __shfl_xor(ss, 1);
        ss += __shfl_xor(ss, 2);
        ss += __shfl_xor(ss, 4);
        ss += __shfl_xor(ss, 8);
        float v = rsqrtf(ss);
        const int row = prow + wave * 16 + g * 4 + r;
        if (!isQ && dmask[row] == 0) v = 0.f;      // zero masked doc tokens
        rn[r] = v;
    }

    unsigned short* P = isQ ? Qb : Db;
    #pragma unroll
    for (int n = 0; n < 8; ++n)
        #pragma unroll
        for (int r = 0; r < 4; ++r) {
            const int row = prow + wave * 16 + g * 4 + r;
            P[(size_t)row * 128 + n * 16 + l] = (unsigned short)f2bf(acc[n][r] * rn[r]);
        }
}

// ---------------------------------------------------------------------------
// Kernel 2: out[b][c] = sum_q max_k(valid) Q[b,q,:] . D[c,k,:]
// 32x32x16 MFMA (q-tile=32=LQ). Wave handles 8 b's as 4 pairs; each D-frag
// ds_read feeds 2 MFMAs. Dlds XOR-swizzled (chunk16 ^= row&15), no pad.
// A: row=lane&31,k=(lane>>5)*8+j.  C/D: col=lane&31(token),
// row=(reg&3)+8*(reg>>2)+4*(lane>>5) (q index).
// ---------------------------------------------------------------------------
__global__ __launch_bounds__(256, 2) void maxsim_kernel(
    const unsigned short* __restrict__ Qb, const unsigned short* __restrict__ Db,
    const int* __restrict__ dmask, float* __restrict__ out)
{
    __shared__ __align__(16) short Dlds[256][128];   // 64 KB, swizzled

    const int tid = threadIdx.x;
    const int wave = tid >> 6, lane = tid & 63;
    const int lo5 = lane & 31, hi = lane >> 5;
    const int c = blockIdx.x & 127;
    const int bg = blockIdx.x >> 7;
    const int sw = lo5 & 15;

    // --- stage D_c swizzled: Dlds[row][ch] holds global chunk ch^(row&15) ---
    {
        const short8* src = reinterpret_cast<const short8*>(Db + (size_t)c * 256 * 128);
        #pragma unroll
        for (int i = 0; i < 16; ++i) {
            int idx = i * 256 + tid;
            int row = idx >> 4, ch = idx & 15;
            short8 v = src[row * 16 + (ch ^ (row & 15))];
            *reinterpret_cast<short8*>(&Dlds[row][ch * 8]) = v;
        }
    }
    // --- validity: token = t*32 + lo5 ---
    unsigned vmask = 0;
    {
        const int* dm = dmask + c * 256;
        #pragma unroll
        for (int t = 0; t < 8; ++t) vmask |= (dm[t * 32 + lo5] != 0 ? 1u : 0u) << t;
    }
    __syncthreads();

    for (int pair = 0; pair < 4; ++pair) {
        const int b0 = bg * 32 + wave * 8 + pair * 2;

        // A-frags for b0, b1 from global (L2-resident): Q[b][lo5][ks*16+hi*8 ..+8]
        short8 a0[8], a1[8];
        const unsigned short* q0 = Qb + ((size_t)b0 * 32 + lo5) * 128 + hi * 8;
        #pragma unroll
        for (int ks = 0; ks < 8; ++ks) {
            a0[ks] = *reinterpret_cast<const short8*>(q0 + ks * 16);
            a1[ks] = *reinterpret_cast<const short8*>(q0 + 4096 + ks * 16);
        }

        float best0[16], best1[16];
        #pragma unroll
        for (int r = 0; r < 16; ++r) { best0[r] = -1e30f; best1[r] = -1e30f; }

        #pragma unroll
        for (int t = 0; t < 8; ++t) {
            f32x16 acc0 = (f32x16)(0.0f);
            f32x16 acc1 = (f32x16)(0.0f);
            #pragma unroll
            for (int ks = 0; ks < 8; ++ks) {
                short8 bf = *reinterpret_cast<const short8*>(
                    &Dlds[t * 32 + lo5][((2 * ks + hi) ^ sw) * 8]);
                acc0 = MFMA32(a0[ks], bf, acc0);
                acc1 = MFMA32(a1[ks], bf, acc1);
            }
            const bool valid = (vmask >> t) & 1;
            #pragma unroll
            for (int r = 0; r < 16; ++r) {
                best0[r] = fmaxf(best0[r], valid ? acc0[r] : -1e30f);
                best1[r] = fmaxf(best1[r], valid ? acc1[r] : -1e30f);
            }
        }

        // max over 32 token-lanes per q, sum q's, then add the other half-wave
        float sum0 = 0.f, sum1 = 0.f;
        #pragma unroll
        for (int r = 0; r < 16; ++r) {
            float v0 = best0[r], v1 = best1[r];
            v0 = fmaxf(v0, __shfl_xor(v0, 1));  v1 = fmaxf(v1, __shfl_xor(v1, 1));
            v0 = fmaxf(v0, __shfl_xor(v0, 2));  v1 = fmaxf(v1, __shfl_xor(v1, 2));
            v0 = fmaxf(v0, __shfl_xor(v0, 4));  v1 = fmaxf(v1, __shfl_xor(v1, 4));
            v0 = fmaxf(v0, __shfl_xor(v0, 8));  v1 = fmaxf(v1, __shfl_xor(v1, 8));
            v0 = fmaxf(v0, __shfl_xor(v0, 16)); v1 = fmaxf(v1, __shfl_xor(v1, 16));
            sum0 += v0; sum1 += v1;
        }
        sum0 += __shfl_xor(sum0, 32);
        sum1 += __shfl_xor(sum1, 32);
        if (lane == 0) {
            out[b0 * 128 + c] = sum0;
            out[(b0 + 1) * 128 + c] = sum1;
        }
    }
}

extern "C" void kernel_launch(void* const* d_in, const int* in_sizes, int n_in,
                              void* d_out, int out_size, void* d_ws, size_t ws_size,
                              hipStream_t stream)
{
    const float* qh    = (const float*)d_in[0];   // [128,32,768]
    const float* dh    = (const float*)d_in[1];   // [128,256,768]
    const float* W     = (const float*)d_in[2];   // [128,768]
    const int*   dmask = (const int*)d_in[3];     // [128,256]
    float* out = (float*)d_out;                   // [128,128]

    unsigned short* Qb = (unsigned short*)d_ws;        // 4096 x 128 bf16 (1 MB)
    unsigned short* Db = Qb + 4096 * 128;              // 32768 x 128 bf16 (8 MB)

    hipLaunchKernelGGL(proj_norm_kernel, dim3(576), dim3(256), 0, stream,
                       qh, dh, W, dmask, Qb, Db);
    hipLaunchKernelGGL(maxsim_kernel, dim3(512), dim3(256), 0, stream,
                       Qb, Db, dmask, out);
}

// Round 4
// 131.111 us; speedup vs baseline: 1.2571x; 1.2571x over previous
//
#include <hip/hip_runtime.h>
#include <hip/hip_bf16.h>

// B=128, LQ=32, LD=256, HID=768, DIM=128
typedef __attribute__((ext_vector_type(8))) short short8;
typedef __attribute__((ext_vector_type(4))) short short4v;
typedef __attribute__((ext_vector_type(4))) float f32x4;
typedef __attribute__((ext_vector_type(16))) float f32x16;

#define MFMA16(a, b, c) __builtin_amdgcn_mfma_f32_16x16x32_bf16(a, b, c, 0, 0, 0)
#define MFMA32(a, b, c) __builtin_amdgcn_mfma_f32_32x32x16_bf16(a, b, c, 0, 0, 0)
#define LGKM0() asm volatile("s_waitcnt lgkmcnt(0)" ::: "memory")
#define RAW_BAR() do { __builtin_amdgcn_sched_barrier(0); \
                       __builtin_amdgcn_s_barrier(); \
                       __builtin_amdgcn_sched_barrier(0); } while (0)

__device__ __forceinline__ short f2bf(float f) {
    union { float f; unsigned u; } x; x.f = f;
    unsigned r = x.u + 0x7fffu + ((x.u >> 16) & 1u);  // RNE
    return (short)(r >> 16);
}

// ---------------------------------------------------------------------------
// Kernel 1: P[row][dim] = l2norm( X[row,:768] @ W[dim,:768]^T ), bf16 out.
// BM=32, BK=32, grid 1152 (4.5 blocks/CU -> TLP hides HBM latency).
// Wave w: rows (w&1)*16..+16, dims (w>>1)*64..+64  (acc = 4 f32x4).
// LDS double-buffer, 1-deep reg prefetch, ONE raw barrier per K-step.
// ---------------------------------------------------------------------------
__global__ __launch_bounds__(256) void proj_norm_kernel(
    const float* __restrict__ qh, const float* __restrict__ dh,
    const float* __restrict__ W, const int* __restrict__ dmask,
    unsigned short* __restrict__ Qb, unsigned short* __restrict__ Db)
{
    __shared__ __align__(16) short Xlds[2][32][40];    // 5.1 KB
    __shared__ __align__(16) short Wlds[2][128][40];   // 20.5 KB
    __shared__ float nbuf[4][16];

    const int tid = threadIdx.x;
    const int wave = tid >> 6, lane = tid & 63;
    const int l = lane & 15, g = lane >> 4;
    const int rw = (wave & 1) * 16, dn = (wave >> 1) * 64;

    const int rowbase = blockIdx.x * 32;            // Q: blocks 0..127, D: 128..1151
    const bool isQ = rowbase < 4096;
    const float* X = isQ ? qh : dh;
    const int prow = isQ ? rowbase : rowbase - 4096;

    const int xrow = tid >> 3, xq = tid & 7;        // X: 8 thr/row, 4 floats each
    const int wrow = tid >> 1, wh = tid & 1;        // W: 2 thr/row, 16 floats each
    const float* xsrc = X + (size_t)(prow + xrow) * 768 + xq * 4;
    const float* wsrc = W + (size_t)wrow * 768 + wh * 16;

    float4 xa, xb, wa[4], wb[4];

    auto loadset = [&](float4& xr, float4 (&wr)[4], int chunk) {
        xr = *reinterpret_cast<const float4*>(xsrc + chunk * 32);
        const float4* ws = reinterpret_cast<const float4*>(wsrc + chunk * 32);
        #pragma unroll
        for (int i = 0; i < 4; ++i) wr[i] = ws[i];
    };
    auto stage = [&](float4& xr, float4 (&wr)[4], int p) {
        short4v xv;
        xv[0]=f2bf(xr.x); xv[1]=f2bf(xr.y); xv[2]=f2bf(xr.z); xv[3]=f2bf(xr.w);
        *reinterpret_cast<short4v*>(&Xlds[p][xrow][xq * 4]) = xv;
        #pragma unroll
        for (int j = 0; j < 2; ++j) {
            short8 v;
            v[0]=f2bf(wr[2*j].x);   v[1]=f2bf(wr[2*j].y);
            v[2]=f2bf(wr[2*j].z);   v[3]=f2bf(wr[2*j].w);
            v[4]=f2bf(wr[2*j+1].x); v[5]=f2bf(wr[2*j+1].y);
            v[6]=f2bf(wr[2*j+1].z); v[7]=f2bf(wr[2*j+1].w);
            *reinterpret_cast<short8*>(&Wlds[p][wrow][wh * 16 + j * 8]) = v;
        }
    };

    f32x4 acc[4];
    #pragma unroll
    for (int n = 0; n < 4; ++n) acc[n] = (f32x4)(0.0f);

    loadset(xa, wa, 0);
    stage(xa, wa, 0);
    loadset(xb, wb, 1);
    LGKM0(); RAW_BAR();

    #pragma unroll
    for (int k = 0; k < 24; ++k) {
        const int p = k & 1;
        short8 af = *reinterpret_cast<const short8*>(&Xlds[p][rw + l][g * 8]);
        #pragma unroll
        for (int n = 0; n < 4; ++n) {
            short8 bf = *reinterpret_cast<const short8*>(&Wlds[p][dn + n * 16 + l][g * 8]);
            acc[n] = MFMA16(af, bf, acc[n]);
        }
        if (k < 23) {
            if (p == 0) {
                stage(xb, wb, 1);
                if (k < 22) loadset(xa, wa, k + 2);
            } else {
                stage(xa, wa, 0);
                if (k < 22) loadset(xb, wb, k + 2);
            }
            LGKM0(); RAW_BAR();
        }
    }

    // --- L2 norm: lane holds C[row=rw+g*4+r][dim=dn+n*16+l] in acc[n][r].
    // In-wave butterfly sums this wave's 64 dims; nbuf combines wave pairs.
    float ss[4];
    #pragma unroll
    for (int r = 0; r < 4; ++r) {
        float s = 0.f;
        #pragma unroll
        for (int n = 0; n < 4; ++n) s += acc[n][r] * acc[n][r];
        s += __shfl_xor(s, 1);
        s += __shfl_xor(s, 2);
        s += __shfl_xor(s, 4);
        s += __shfl_xor(s, 8);
        ss[r] = s;
    }
    if (l == 0) {
        #pragma unroll
        for (int r = 0; r < 4; ++r) nbuf[wave][g * 4 + r] = ss[r];
    }
    __syncthreads();

    unsigned short* P = isQ ? Qb : Db;
    #pragma unroll
    for (int r = 0; r < 4; ++r) {
        const int row = prow + rw + g * 4 + r;
        float tot = ss[r] + nbuf[wave ^ 2][g * 4 + r];
        float rn = rsqrtf(tot);
        if (!isQ && dmask[row] == 0) rn = 0.f;
        #pragma unroll
        for (int n = 0; n < 4; ++n)
            P[(size_t)row * 128 + dn + n * 16 + l] = (unsigned short)f2bf(acc[n][r] * rn);
    }
}

// ---------------------------------------------------------------------------
// Kernel 2: out[b][c] = sum_q max_k(valid) Q[b,q,:] . D[c,k,:]
// 32x32x16 MFMA, ONE b at a time (register-lean), t-PAIRED acc chains for
// ILP. Dlds XOR-swizzled (chunk ^= row&15). Live regs ~100 -> no spills.
// ---------------------------------------------------------------------------
__global__ __launch_bounds__(256) void maxsim_kernel(
    const unsigned short* __restrict__ Qb, const unsigned short* __restrict__ Db,
    const int* __restrict__ dmask, float* __restrict__ out)
{
    __shared__ __align__(16) short Dlds[256][128];   // 64 KB, swizzled

    const int tid = threadIdx.x;
    const int wave = tid >> 6, lane = tid & 63;
    const int lo5 = lane & 31, hi = lane >> 5;
    const int c = blockIdx.x & 127;
    const int bg = blockIdx.x >> 7;
    const int sw = lo5 & 15;

    // --- stage D_c swizzled: Dlds[row][ch] holds global chunk ch^(row&15) ---
    {
        const short8* src = reinterpret_cast<const short8*>(Db + (size_t)c * 256 * 128);
        #pragma unroll
        for (int i = 0; i < 16; ++i) {
            int idx = i * 256 + tid;
            int row = idx >> 4, ch = idx & 15;
            short8 v = src[row * 16 + (ch ^ (row & 15))];
            *reinterpret_cast<short8*>(&Dlds[row][ch * 8]) = v;
        }
    }
    // --- validity: token = t*32 + lo5, t = 0..7 ---
    unsigned vmask = 0;
    {
        const int* dm = dmask + c * 256;
        #pragma unroll
        for (int t = 0; t < 8; ++t) vmask |= (dm[t * 32 + lo5] != 0 ? 1u : 0u) << t;
    }
    __syncthreads();

    for (int ib = 0; ib < 8; ++ib) {
        const int b = bg * 32 + wave * 8 + ib;

        // A-frags (Q for this b), L2-resident: Q[b][lo5][ks*16 + hi*8 ..+8]
        short8 a[8];
        const unsigned short* qp = Qb + ((size_t)b * 32 + lo5) * 128 + hi * 8;
        #pragma unroll
        for (int ks = 0; ks < 8; ++ks)
            a[ks] = *reinterpret_cast<const short8*>(qp + ks * 16);

        float best[16];
        #pragma unroll
        for (int r = 0; r < 16; ++r) best[r] = -1e30f;

        #pragma unroll
        for (int tp = 0; tp < 4; ++tp) {           // token tiles 2tp, 2tp+1
            f32x16 acc0 = (f32x16)(0.0f);
            f32x16 acc1 = (f32x16)(0.0f);
            #pragma unroll
            for (int ks = 0; ks < 8; ++ks) {
                const int chs = ((2 * ks + hi) ^ sw) * 8;
                short8 bf0 = *reinterpret_cast<const short8*>(&Dlds[tp * 64 + lo5][chs]);
                short8 bf1 = *reinterpret_cast<const short8*>(&Dlds[tp * 64 + 32 + lo5][chs]);
                acc0 = MFMA32(a[ks], bf0, acc0);
                acc1 = MFMA32(a[ks], bf1, acc1);
            }
            const bool v0 = (vmask >> (2 * tp)) & 1;
            const bool v1 = (vmask >> (2 * tp + 1)) & 1;
            #pragma unroll
            for (int r = 0; r < 16; ++r) {
                best[r] = fmaxf(best[r], v0 ? acc0[r] : -1e30f);
                best[r] = fmaxf(best[r], v1 ? acc1[r] : -1e30f);
            }
        }

        // max over 32 token-lanes per q, sum q's, add other half-wave
        float sum = 0.f;
        #pragma unroll
        for (int r = 0; r < 16; ++r) {
            float v = best[r];
            v = fmaxf(v, __shfl_xor(v, 1));
            v = fmaxf(v, __shfl_xor(v, 2));
            v = fmaxf(v, __shfl_xor(v, 4));
            v = fmaxf(v, __shfl_xor(v, 8));
            v = fmaxf(v, __shfl_xor(v, 16));
            sum += v;   // q = (r&3) + 8*(r>>2) + 4*hi
        }
        sum += __shfl_xor(sum, 32);
        if (lane == 0) out[b * 128 + c] = sum;
    }
}

extern "C" void kernel_launch(void* const* d_in, const int* in_sizes, int n_in,
                              void* d_out, int out_size, void* d_ws, size_t ws_size,
                              hipStream_t stream)
{
    const float* qh    = (const float*)d_in[0];   // [128,32,768]
    const float* dh    = (const float*)d_in[1];   // [128,256,768]
    const float* W     = (const float*)d_in[2];   // [128,768]
    const int*   dmask = (const int*)d_in[3];     // [128,256]
    float* out = (float*)d_out;                   // [128,128]

    unsigned short* Qb = (unsigned short*)d_ws;        // 4096 x 128 bf16 (1 MB)
    unsigned short* Db = Qb + 4096 * 128;              // 32768 x 128 bf16 (8 MB)

    // 36864 rows / 32 rows-per-block = 1152 blocks
    hipLaunchKernelGGL(proj_norm_kernel, dim3(1152), dim3(256), 0, stream,
                       qh, dh, W, dmask, Qb, Db);
    // 128 docs x 4 b-groups
    hipLaunchKernelGGL(maxsim_kernel, dim3(512), dim3(256), 0, stream,
                       Qb, Db, dmask, out);
}

// Round 5
// 78.940 us; speedup vs baseline: 2.0879x; 1.6609x over previous
//
#include <hip/hip_runtime.h>
#include <hip/hip_bf16.h>

// B=128, LQ=32, LD=256, HID=768, DIM=128
typedef __attribute__((ext_vector_type(8))) short short8;
typedef __attribute__((ext_vector_type(4))) short short4v;
typedef __attribute__((ext_vector_type(4))) float f32x4;
typedef __attribute__((ext_vector_type(16))) float f32x16;

#define MFMA16(a, b, c) __builtin_amdgcn_mfma_f32_16x16x32_bf16(a, b, c, 0, 0, 0)
#define MFMA32(a, b, c) __builtin_amdgcn_mfma_f32_32x32x16_bf16(a, b, c, 0, 0, 0)
#define LGKM0() asm volatile("s_waitcnt lgkmcnt(0)" ::: "memory")
#define RAW_BAR() do { __builtin_amdgcn_sched_barrier(0); \
                       __builtin_amdgcn_s_barrier(); \
                       __builtin_amdgcn_sched_barrier(0); } while (0)

__device__ __forceinline__ short f2bf(float f) {
    union { float f; unsigned u; } x; x.f = f;
    unsigned r = x.u + 0x7fffu + ((x.u >> 16) & 1u);  // RNE
    return (short)(r >> 16);
}

// ---------------------------------------------------------------------------
// Kernel 1 (unchanged from R4): P[row][dim] = l2norm(X[row] @ W^T), bf16 out.
// ---------------------------------------------------------------------------
__global__ __launch_bounds__(256) void proj_norm_kernel(
    const float* __restrict__ qh, const float* __restrict__ dh,
    const float* __restrict__ W, const int* __restrict__ dmask,
    unsigned short* __restrict__ Qb, unsigned short* __restrict__ Db)
{
    __shared__ __align__(16) short Xlds[2][32][40];
    __shared__ __align__(16) short Wlds[2][128][40];
    __shared__ float nbuf[4][16];

    const int tid = threadIdx.x;
    const int wave = tid >> 6, lane = tid & 63;
    const int l = lane & 15, g = lane >> 4;
    const int rw = (wave & 1) * 16, dn = (wave >> 1) * 64;

    const int rowbase = blockIdx.x * 32;
    const bool isQ = rowbase < 4096;
    const float* X = isQ ? qh : dh;
    const int prow = isQ ? rowbase : rowbase - 4096;

    const int xrow = tid >> 3, xq = tid & 7;
    const int wrow = tid >> 1, wh = tid & 1;
    const float* xsrc = X + (size_t)(prow + xrow) * 768 + xq * 4;
    const float* wsrc = W + (size_t)wrow * 768 + wh * 16;

    float4 xa, xb, wa[4], wb[4];

    auto loadset = [&](float4& xr, float4 (&wr)[4], int chunk) {
        xr = *reinterpret_cast<const float4*>(xsrc + chunk * 32);
        const float4* ws = reinterpret_cast<const float4*>(wsrc + chunk * 32);
        #pragma unroll
        for (int i = 0; i < 4; ++i) wr[i] = ws[i];
    };
    auto stage = [&](float4& xr, float4 (&wr)[4], int p) {
        short4v xv;
        xv[0]=f2bf(xr.x); xv[1]=f2bf(xr.y); xv[2]=f2bf(xr.z); xv[3]=f2bf(xr.w);
        *reinterpret_cast<short4v*>(&Xlds[p][xrow][xq * 4]) = xv;
        #pragma unroll
        for (int j = 0; j < 2; ++j) {
            short8 v;
            v[0]=f2bf(wr[2*j].x);   v[1]=f2bf(wr[2*j].y);
            v[2]=f2bf(wr[2*j].z);   v[3]=f2bf(wr[2*j].w);
            v[4]=f2bf(wr[2*j+1].x); v[5]=f2bf(wr[2*j+1].y);
            v[6]=f2bf(wr[2*j+1].z); v[7]=f2bf(wr[2*j+1].w);
            *reinterpret_cast<short8*>(&Wlds[p][wrow][wh * 16 + j * 8]) = v;
        }
    };

    f32x4 acc[4];
    #pragma unroll
    for (int n = 0; n < 4; ++n) acc[n] = (f32x4)(0.0f);

    loadset(xa, wa, 0);
    stage(xa, wa, 0);
    loadset(xb, wb, 1);
    LGKM0(); RAW_BAR();

    #pragma unroll
    for (int k = 0; k < 24; ++k) {
        const int p = k & 1;
        short8 af = *reinterpret_cast<const short8*>(&Xlds[p][rw + l][g * 8]);
        #pragma unroll
        for (int n = 0; n < 4; ++n) {
            short8 bf = *reinterpret_cast<const short8*>(&Wlds[p][dn + n * 16 + l][g * 8]);
            acc[n] = MFMA16(af, bf, acc[n]);
        }
        if (k < 23) {
            if (p == 0) {
                stage(xb, wb, 1);
                if (k < 22) loadset(xa, wa, k + 2);
            } else {
                stage(xa, wa, 0);
                if (k < 22) loadset(xb, wb, k + 2);
            }
            LGKM0(); RAW_BAR();
        }
    }

    float ss[4];
    #pragma unroll
    for (int r = 0; r < 4; ++r) {
        float s = 0.f;
        #pragma unroll
        for (int n = 0; n < 4; ++n) s += acc[n][r] * acc[n][r];
        s += __shfl_xor(s, 1);
        s += __shfl_xor(s, 2);
        s += __shfl_xor(s, 4);
        s += __shfl_xor(s, 8);
        ss[r] = s;
    }
    if (l == 0) {
        #pragma unroll
        for (int r = 0; r < 4; ++r) nbuf[wave][g * 4 + r] = ss[r];
    }
    __syncthreads();

    unsigned short* P = isQ ? Qb : Db;
    #pragma unroll
    for (int r = 0; r < 4; ++r) {
        const int row = prow + rw + g * 4 + r;
        float tot = ss[r] + nbuf[wave ^ 2][g * 4 + r];
        float rn = rsqrtf(tot);
        if (!isQ && dmask[row] == 0) rn = 0.f;
        #pragma unroll
        for (int n = 0; n < 4; ++n)
            P[(size_t)row * 128 + dn + n * 16 + l] = (unsigned short)f2bf(acc[n][r] * rn);
    }
}

// ---------------------------------------------------------------------------
// Kernel 1.5: in-place compaction of Db per doc c: valid rows first (stable),
// remaining slots filled with a copy of token 0 (guaranteed valid; duplicates
// cannot change a max). Removes ALL masking from maxsim + enables early exit.
// ---------------------------------------------------------------------------
__global__ __launch_bounds__(256) void compact_kernel(
    const int* __restrict__ dmask, unsigned short* __restrict__ Db)
{
    __shared__ __align__(16) short rows[256][128];   // 64 KB
    __shared__ int wcnt[4];

    const int c = blockIdx.x;
    const int tid = threadIdx.x;
    const int wave = tid >> 6, lane = tid & 63;

    // coalesced load of D_c into LDS (chunk-swizzled: LDS[row][i^(row&15)] = chunk i)
    short8* ldsf = reinterpret_cast<short8*>(&rows[0][0]);
    const short8* src = reinterpret_cast<const short8*>(Db + (size_t)c * 256 * 128);
    #pragma unroll
    for (int i = 0; i < 16; ++i) {
        int idx = i * 256 + tid;
        int row = idx >> 4, ch = idx & 15;
        ldsf[row * 16 + (ch ^ (row & 15))] = src[idx];
    }

    const bool valid = dmask[c * 256 + tid] != 0;
    unsigned long long bal = __ballot(valid);
    const int before = __popcll(bal & ((1ull << lane) - 1ull));
    if (lane == 0) wcnt[wave] = __popcll(bal);
    __syncthreads();

    int base = 0, nv = 0;
    #pragma unroll
    for (int w = 0; w < 4; ++w) { int v = wcnt[w]; nv += v; if (w < wave) base += v; }
    const int myrank = valid ? (base + before) : (nv + (tid - base - before));
    const int srcrow = valid ? tid : 0;   // pads duplicate token 0 (always valid)

    short8* dst = reinterpret_cast<short8*>(Db + (size_t)(c * 256 + myrank) * 128);
    #pragma unroll
    for (int i = 0; i < 16; ++i)
        dst[i] = *reinterpret_cast<const short8*>(&rows[srcrow][(i ^ (srcrow & 15)) * 8]);
}

// ---------------------------------------------------------------------------
// Kernel 2: out[b][c] = sum_q max_k Q[b,q,:] . Dc[c,k,:]   (Dc compacted)
// Operand-SWAPPED 32x32x16 MFMA: A = D tokens (M), B = Q (N=q), K=dim.
// C/D: col=lane&31 = q  -> max over tokens is IN-LANE; one butterfly per b.
// 512 thr (8 waves), wave owns one b. Dynamic tile-pair count = ceil(nv/64).
// ---------------------------------------------------------------------------
__global__ __launch_bounds__(512) void maxsim_kernel(
    const unsigned short* __restrict__ Qb, const unsigned short* __restrict__ Db,
    const int* __restrict__ dmask, float* __restrict__ out)
{
    __shared__ __align__(16) short Dlds[256][128];   // 64 KB, swizzled
    __shared__ int wcnt[4];

    const int tid = threadIdx.x;
    const int wave = tid >> 6, lane = tid & 63;
    const int lo5 = lane & 31, hi = lane >> 5;
    const int c  = blockIdx.x & 127;
    const int bg = blockIdx.x >> 7;           // 0..15
    const int b  = bg * 8 + wave;

    // stage D_c swizzled: Dlds[row][ch] = global chunk ch^(row&15)
    {
        const short8* src = reinterpret_cast<const short8*>(Db + (size_t)c * 256 * 128);
        #pragma unroll
        for (int i = 0; i < 8; ++i) {
            int idx = i * 512 + tid;
            int row = idx >> 4, ch = idx & 15;
            short8 v = src[row * 16 + (ch ^ (row & 15))];
            *reinterpret_cast<short8*>(&Dlds[row][ch * 8]) = v;
        }
    }
    // count valid tokens (waves 0-3 cover tokens 0..255)
    if (tid < 256) {
        bool valid = dmask[c * 256 + tid] != 0;
        unsigned long long bal = __ballot(valid);
        if (lane == 0) wcnt[wave] = __popcll(bal);
    }
    __syncthreads();
    const int nv = wcnt[0] + wcnt[1] + wcnt[2] + wcnt[3];
    const int npairs = (nv + 63) >> 6;        // 1..4 tile-pairs of 64 tokens

    // Q fragments (B operand): q = lo5, k = ks*16 + hi*8 + j   (L2-resident)
    short8 a[8];
    const unsigned short* qp = Qb + ((size_t)b * 32 + lo5) * 128 + hi * 8;
    #pragma unroll
    for (int ks = 0; ks < 8; ++ks)
        a[ks] = *reinterpret_cast<const short8*>(qp + ks * 16);

    const int sw = lo5 & 15;
    float m = -1e30f;

    for (int p = 0; p < npairs; ++p) {
        f32x16 acc0 = (f32x16)(0.0f), acc1 = (f32x16)(0.0f);
        #pragma unroll
        for (int ks = 0; ks < 8; ++ks) {
            const int chs = ((2 * ks + hi) ^ sw) * 8;
            short8 d0 = *reinterpret_cast<const short8*>(&Dlds[p * 64 + lo5][chs]);
            short8 d1 = *reinterpret_cast<const short8*>(&Dlds[p * 64 + 32 + lo5][chs]);
            acc0 = MFMA32(d0, a[ks], acc0);   // A = D tokens, B = Q
            acc1 = MFMA32(d1, a[ks], acc1);
        }
        // in-lane max over the 32 token-rows of this pair
        #pragma unroll
        for (int r = 0; r < 16; ++r)
            m = fmaxf(m, fmaxf(acc0[r], acc1[r]));
    }

    // merge the two row-halves (same q, different tokens), then sum over q
    m = fmaxf(m, __shfl_xor(m, 32));
    float s = m;
    s += __shfl_xor(s, 1);
    s += __shfl_xor(s, 2);
    s += __shfl_xor(s, 4);
    s += __shfl_xor(s, 8);
    s += __shfl_xor(s, 16);
    if (lane == 0) out[b * 128 + c] = s;
}

extern "C" void kernel_launch(void* const* d_in, const int* in_sizes, int n_in,
                              void* d_out, int out_size, void* d_ws, size_t ws_size,
                              hipStream_t stream)
{
    const float* qh    = (const float*)d_in[0];   // [128,32,768]
    const float* dh    = (const float*)d_in[1];   // [128,256,768]
    const float* W     = (const float*)d_in[2];   // [128,768]
    const int*   dmask = (const int*)d_in[3];     // [128,256]
    float* out = (float*)d_out;                   // [128,128]

    unsigned short* Qb = (unsigned short*)d_ws;        // 4096 x 128 bf16 (1 MB)
    unsigned short* Db = Qb + 4096 * 128;              // 32768 x 128 bf16 (8 MB)

    hipLaunchKernelGGL(proj_norm_kernel, dim3(1152), dim3(256), 0, stream,
                       qh, dh, W, dmask, Qb, Db);
    hipLaunchKernelGGL(compact_kernel, dim3(128), dim3(256), 0, stream,
                       dmask, Db);
    hipLaunchKernelGGL(maxsim_kernel, dim3(2048), dim3(512), 0, stream,
                       Qb, Db, dmask, out);
}

// Round 6
// 71.542 us; speedup vs baseline: 2.3038x; 1.1034x over previous
//
#include <hip/hip_runtime.h>
#include <hip/hip_bf16.h>

// B=128, LQ=32, LD=256, HID=768, DIM=128
typedef __attribute__((ext_vector_type(8))) short short8;
typedef __attribute__((ext_vector_type(4))) float f32x4;
typedef __attribute__((ext_vector_type(16))) float f32x16;

#define MFMA16(a, b, c) __builtin_amdgcn_mfma_f32_16x16x32_bf16(a, b, c, 0, 0, 0)
#define MFMA32(a, b, c) __builtin_amdgcn_mfma_f32_32x32x16_bf16(a, b, c, 0, 0, 0)
#define LGKM0() asm volatile("s_waitcnt lgkmcnt(0)" ::: "memory")
#define RAW_BAR() do { __builtin_amdgcn_sched_barrier(0); \
                       __builtin_amdgcn_s_barrier(); \
                       __builtin_amdgcn_sched_barrier(0); } while (0)

__device__ __forceinline__ short f2bf(float f) {
    union { float f; unsigned u; } x; x.f = f;
    unsigned r = x.u + 0x7fffu + ((x.u >> 16) & 1u);  // RNE
    return (short)(r >> 16);
}

__device__ __forceinline__ short8 cvt8(const float4& a, const float4& b) {
    short8 v;
    v[0]=f2bf(a.x); v[1]=f2bf(a.y); v[2]=f2bf(a.z); v[3]=f2bf(a.w);
    v[4]=f2bf(b.x); v[5]=f2bf(b.y); v[6]=f2bf(b.z); v[7]=f2bf(b.w);
    return v;
}

// ---------------------------------------------------------------------------
// Kernel 0: W [128x768] fp32 -> bf16 fragment-image.
// Image slot s = (kc*16 + f)*64 + lane  (kc=K-chunk/64, f=ks*8+n) holds the
// 8 bf16 of B-frag element: dim=(f&7)*16+(lane&15), k=kc*64+(f>>3)*32+(lane>>4)*8+j.
// So per-K-chunk staging into LDS is a LINEAR 16 KB copy (global_load_lds-able).
// ---------------------------------------------------------------------------
__global__ __launch_bounds__(256) void wprep_kernel(
    const float* __restrict__ W, unsigned short* __restrict__ Wimg)
{
    const int gt = blockIdx.x * 256 + threadIdx.x;    // 0..12287
    const int kc = gt >> 10, rem = gt & 1023;
    const int f = rem >> 6, lane = rem & 63;
    const int dim = (f & 7) * 16 + (lane & 15);
    const int kb  = kc * 64 + (f >> 3) * 32 + (lane >> 4) * 8;
    const float4* s = reinterpret_cast<const float4*>(W + dim * 768 + kb);
    float4 a = s[0], b = s[1];
    *reinterpret_cast<short8*>(Wimg + (size_t)gt * 8) = cvt8(a, b);
}

// ---------------------------------------------------------------------------
// Kernel 1: P[row][dim] = l2norm( X[row,:768] @ W[dim,:768]^T ), bf16 out.
// BM=64, BK=64, 12 K-steps, 4 waves (wave owns 16 rows x 128 dims).
// W: global_load_lds (16B) from pre-converted frag-image, double-buffered.
// X: reg-staged fp32->bf16, triple-buffered regs (issued 2 iters ahead).
// Counted vmcnt(4) before each raw barrier: X-next loads stay in flight.
// ---------------------------------------------------------------------------
__global__ __launch_bounds__(256) void proj_norm_kernel(
    const float* __restrict__ qh, const float* __restrict__ dh,
    const unsigned short* __restrict__ Wimg, const int* __restrict__ dmask,
    unsigned short* __restrict__ Qb, unsigned short* __restrict__ Db)
{
    __shared__ __align__(16) short Xl[2][64][72];   // 18.4 KB (72: pad, spreads rows over banks)
    __shared__ __align__(16) short Wl[2][8192];     // 32 KB (frag image, linear)

    const int tid = threadIdx.x;
    const int wave = tid >> 6, lane = tid & 63;
    const int l = lane & 15, g = lane >> 4;

    const int rowbase = blockIdx.x * 64;            // Q: blocks 0..63, D: 64..575
    const bool isQ = rowbase < 4096;
    const float* X = isQ ? qh : dh;
    const int prow = isQ ? rowbase : rowbase - 4096;

    const int xr = tid >> 2, xq = tid & 3;          // X: 4 thr/row, 16 floats each
    const float* xsrc = X + (size_t)(prow + xr) * 768 + xq * 16;

    f32x4 acc[8];
    #pragma unroll
    for (int n = 0; n < 8; ++n) acc[n] = (f32x4)(0.0f);

    float4 xg[3][4];

    auto xload = [&](float4 (&xb)[4], int k) {
        const float4* s = reinterpret_cast<const float4*>(xsrc + k * 64);
        #pragma unroll
        for (int i = 0; i < 4; ++i) xb[i] = s[i];
    };
    auto xstage = [&](float4 (&xb)[4], int p) {
        *reinterpret_cast<short8*>(&Xl[p][xr][xq * 16])     = cvt8(xb[0], xb[1]);
        *reinterpret_cast<short8*>(&Xl[p][xr][xq * 16 + 8]) = cvt8(xb[2], xb[3]);
    };
    auto wstage = [&](int kc, int p) {              // 4x global_load_lds width-16
        const unsigned short* src = Wimg + (size_t)kc * 8192 + (wave * 64 + lane) * 8;
        short* base = &Wl[p][wave * 512];           // wave-uniform; HW adds lane*16B
        #pragma unroll
        for (int i = 0; i < 4; ++i)
            __builtin_amdgcn_global_load_lds(
                (const __attribute__((address_space(1))) void*)(src + i * 2048),
                (__attribute__((address_space(3))) void*)(base + i * 2048), 16, 0, 0);
    };
    auto compute = [&](int p) {
        const int r = wave * 16 + l;
        #pragma unroll
        for (int ks = 0; ks < 2; ++ks) {
            short8 af = *reinterpret_cast<const short8*>(&Xl[p][r][ks * 32 + g * 8]);
            #pragma unroll
            for (int n = 0; n < 8; ++n) {
                short8 wf = *reinterpret_cast<const short8*>(&Wl[p][(ks * 8 + n) * 512 + lane * 8]);
                acc[n] = MFMA16(af, wf, acc[n]);
            }
        }
    };

    // --- prologue: W0 -> Wl[0] (gld_lds), X0,X1 -> regs; stage X0 ---
    wstage(0, 0);
    xload(xg[0], 0);
    xload(xg[1], 1);
    xstage(xg[0], 0);          // compiler-counted vmcnt drains W0-gld + X0 here
    LGKM0(); RAW_BAR();

    #pragma unroll
    for (int k = 0; k < 12; ++k) {
        const int p = k & 1;
        if (k < 11) wstage(k + 1, p ^ 1);           // Wl[p^1] freed by last barrier
        if (k < 10) xload(xg[(k + 2) % 3], k + 2);  // 2-iters-ahead HBM prefetch
        compute(p);
        if (k < 11) {
            xstage(xg[(k + 1) % 3], p ^ 1);         // compiler waits X(k+1) only
            if (k < 10) { asm volatile("s_waitcnt vmcnt(4)" ::: "memory"); }  // W(k+1) landed; X(k+2) in flight
            else        { asm volatile("s_waitcnt vmcnt(0)" ::: "memory"); }
            LGKM0(); RAW_BAR();
        }
    }

    // --- L2 norm: lane holds C[row=g*4+r][dim=n*16+l] in acc[n][r] ---
    float rn[4];
    #pragma unroll
    for (int r = 0; r < 4; ++r) {
        float ss = 0.f;
        #pragma unroll
        for (int n = 0; n < 8; ++n) ss += acc[n][r] * acc[n][r];
        ss += __shfl_xor(ss, 1);
        ss += __shfl_xor(ss, 2);
        ss += __shfl_xor(ss, 4);
        ss += __shfl_xor(ss, 8);
        float v = rsqrtf(ss);
        const int row = prow + wave * 16 + g * 4 + r;
        if (!isQ && dmask[row] == 0) v = 0.f;       // zero masked doc tokens
        rn[r] = v;
    }

    unsigned short* P = isQ ? Qb : Db;
    #pragma unroll
    for (int n = 0; n < 8; ++n)
        #pragma unroll
        for (int r = 0; r < 4; ++r) {
            const int row = prow + wave * 16 + g * 4 + r;
            P[(size_t)row * 128 + n * 16 + l] = (unsigned short)f2bf(acc[n][r] * rn[r]);
        }
}

// ---------------------------------------------------------------------------
// Kernel 1.5 (unchanged): in-place per-doc compaction of Db; valid rows first,
// padding duplicates token 0 (always valid; duplicates can't change a max).
// ---------------------------------------------------------------------------
__global__ __launch_bounds__(256) void compact_kernel(
    const int* __restrict__ dmask, unsigned short* __restrict__ Db)
{
    __shared__ __align__(16) short rows[256][128];
    __shared__ int wcnt[4];

    const int c = blockIdx.x;
    const int tid = threadIdx.x;
    const int wave = tid >> 6, lane = tid & 63;

    short8* ldsf = reinterpret_cast<short8*>(&rows[0][0]);
    const short8* src = reinterpret_cast<const short8*>(Db + (size_t)c * 256 * 128);
    #pragma unroll
    for (int i = 0; i < 16; ++i) {
        int idx = i * 256 + tid;
        int row = idx >> 4, ch = idx & 15;
        ldsf[row * 16 + (ch ^ (row & 15))] = src[idx];
    }

    const bool valid = dmask[c * 256 + tid] != 0;
    unsigned long long bal = __ballot(valid);
    const int before = __popcll(bal & ((1ull << lane) - 1ull));
    if (lane == 0) wcnt[wave] = __popcll(bal);
    __syncthreads();

    int base = 0, nv = 0;
    #pragma unroll
    for (int w = 0; w < 4; ++w) { int v = wcnt[w]; nv += v; if (w < wave) base += v; }
    const int myrank = valid ? (base + before) : (nv + (tid - base - before));
    const int srcrow = valid ? tid : 0;

    short8* dst = reinterpret_cast<short8*>(Db + (size_t)(c * 256 + myrank) * 128);
    #pragma unroll
    for (int i = 0; i < 16; ++i)
        dst[i] = *reinterpret_cast<const short8*>(&rows[srcrow][(i ^ (srcrow & 15)) * 8]);
}

// ---------------------------------------------------------------------------
// Kernel 2 (unchanged): out[b][c] = sum_q max_k Q[b,q,:] . Dc[c,k,:]
// Operand-swapped 32x32x16 (A=D tokens, B=Q): max over tokens is IN-LANE.
// ---------------------------------------------------------------------------
__global__ __launch_bounds__(512) void maxsim_kernel(
    const unsigned short* __restrict__ Qb, const unsigned short* __restrict__ Db,
    const int* __restrict__ dmask, float* __restrict__ out)
{
    __shared__ __align__(16) short Dlds[256][128];
    __shared__ int wcnt[4];

    const int tid = threadIdx.x;
    const int wave = tid >> 6, lane = tid & 63;
    const int lo5 = lane & 31, hi = lane >> 5;
    const int c  = blockIdx.x & 127;
    const int bg = blockIdx.x >> 7;
    const int b  = bg * 8 + wave;

    {
        const short8* src = reinterpret_cast<const short8*>(Db + (size_t)c * 256 * 128);
        #pragma unroll
        for (int i = 0; i < 8; ++i) {
            int idx = i * 512 + tid;
            int row = idx >> 4, ch = idx & 15;
            short8 v = src[row * 16 + (ch ^ (row & 15))];
            *reinterpret_cast<short8*>(&Dlds[row][ch * 8]) = v;
        }
    }
    if (tid < 256) {
        bool valid = dmask[c * 256 + tid] != 0;
        unsigned long long bal = __ballot(valid);
        if (lane == 0) wcnt[wave] = __popcll(bal);
    }
    __syncthreads();
    const int nv = wcnt[0] + wcnt[1] + wcnt[2] + wcnt[3];
    const int npairs = (nv + 63) >> 6;

    short8 a[8];
    const unsigned short* qp = Qb + ((size_t)b * 32 + lo5) * 128 + hi * 8;
    #pragma unroll
    for (int ks = 0; ks < 8; ++ks)
        a[ks] = *reinterpret_cast<const short8*>(qp + ks * 16);

    const int sw = lo5 & 15;
    float m = -1e30f;

    for (int p = 0; p < npairs; ++p) {
        f32x16 acc0 = (f32x16)(0.0f), acc1 = (f32x16)(0.0f);
        #pragma unroll
        for (int ks = 0; ks < 8; ++ks) {
            const int chs = ((2 * ks + hi) ^ sw) * 8;
            short8 d0 = *reinterpret_cast<const short8*>(&Dlds[p * 64 + lo5][chs]);
            short8 d1 = *reinterpret_cast<const short8*>(&Dlds[p * 64 + 32 + lo5][chs]);
            acc0 = MFMA32(d0, a[ks], acc0);
            acc1 = MFMA32(d1, a[ks], acc1);
        }
        #pragma unroll
        for (int r = 0; r < 16; ++r)
            m = fmaxf(m, fmaxf(acc0[r], acc1[r]));
    }

    m = fmaxf(m, __shfl_xor(m, 32));
    float s = m;
    s += __shfl_xor(s, 1);
    s += __shfl_xor(s, 2);
    s += __shfl_xor(s, 4);
    s += __shfl_xor(s, 8);
    s += __shfl_xor(s, 16);
    if (lane == 0) out[b * 128 + c] = s;
}

extern "C" void kernel_launch(void* const* d_in, const int* in_sizes, int n_in,
                              void* d_out, int out_size, void* d_ws, size_t ws_size,
                              hipStream_t stream)
{
    const float* qh    = (const float*)d_in[0];   // [128,32,768]
    const float* dh    = (const float*)d_in[1];   // [128,256,768]
    const float* W     = (const float*)d_in[2];   // [128,768]
    const int*   dmask = (const int*)d_in[3];     // [128,256]
    float* out = (float*)d_out;                   // [128,128]

    unsigned short* Qb   = (unsigned short*)d_ws;       // 4096x128 bf16 (1 MB)
    unsigned short* Db   = Qb + 4096 * 128;             // 32768x128 bf16 (8 MB)
    unsigned short* Wimg = Db + (size_t)32768 * 128;    // 12288x8 bf16 (196 KB)

    hipLaunchKernelGGL(wprep_kernel, dim3(48), dim3(256), 0, stream, W, Wimg);
    hipLaunchKernelGGL(proj_norm_kernel, dim3(576), dim3(256), 0, stream,
                       qh, dh, Wimg, dmask, Qb, Db);
    hipLaunchKernelGGL(compact_kernel, dim3(128), dim3(256), 0, stream,
                       dmask, Db);
    hipLaunchKernelGGL(maxsim_kernel, dim3(2048), dim3(512), 0, stream,
                       Qb, Db, dmask, out);
}